// Round 9
// baseline (56.430 us; speedup 1.0000x reference)
//
#include <hip/hip_runtime.h>

// ShiftMap fused, v9 = v8 skeleton + VALU-cut:
//  - per-x bicubic weight table (float4, 16KB, L1-resident) from a tiny setup
//    kernel: wx weights + cx0 are identical across all rows/batches.
//  - packed fp32 (v_pk_fma_f32 via ext_vector float2) for gather weights
//    (gwx,gwy evaluated together), x-interp of control row, and coords.
//  - control row staged pre-scaled and channel-swapped: (smx*half_w, smy*half_h).
//  - single kernel structure, interior fast path w/ dwordx4 row-loads,
//    XCD-aware swizzle (each batch's 4MB image in one XCD's L2).

static constexpr float A = -0.75f;  // PyTorch bicubic coefficient
static constexpr int NXCD = 8;

typedef float f4u __attribute__((ext_vector_type(4), aligned(4)));
typedef float f4a __attribute__((ext_vector_type(4), aligned(16)));
typedef float f2  __attribute__((ext_vector_type(2)));

__device__ __forceinline__ void cubic_weights(float t, float* w) {
    const float tm1 = t - 1.0f;
    const float p   = t * tm1;
    w[0] = (A * p) * tm1;           // A t (t-1)^2
    w[3] = (-A * p) * t;            // A t^2 (1-t)
    const float t2 = t * t;
    w[1] = (A + 2.0f) * t2 * t - (A + 3.0f) * t2 + 1.0f;
    w[2] = 1.0f - w[0] - w[1] - w[3];
}

// packed pair: t = (tx, ty) -> w[j] = (wx_j, wy_j)
__device__ __forceinline__ void cubic_weights_pk(f2 t, f2* w) {
    const f2 tm1 = t - 1.0f;
    const f2 p   = t * tm1;
    w[0] = (A * p) * tm1;
    w[3] = (-A * p) * t;
    const f2 t2 = t * t;
    w[1] = (A + 2.0f) * t2 * t - (A + 3.0f) * t2 + 1.0f;
    w[2] = 1.0f - w[0] - w[1] - w[3];
}

// ---- setup: per-x weight table (runs once, 4 blocks) ----
__global__ __launch_bounds__(256) void wxtab_kernel(
    f4a* __restrict__ tab, int W, float scale_x)
{
    const int x = blockIdx.x * 256 + threadIdx.x;
    if (x >= W) return;
    const float sx = x * scale_x;
    const float t  = sx - floorf(sx);
    float w[4];
    cubic_weights(t, w);
    f4a v; v.x = w[0]; v.y = w[1]; v.z = w[2]; v.w = w[3];
    tab[x] = v;
}

// ---- main kernel ----
template <int PX>
__global__ __launch_bounds__(256) void shiftmap_warp_kernel(
    const float* __restrict__ img,   // (B,1,H,W)
    const float* __restrict__ smap,  // (B,CH,CW,2)
    const f4a* __restrict__ wxtab,   // (W)
    float* __restrict__ out,         // (B,1,H,W)
    int H, int W, int CH, int CW, int nblocks,
    float scale_y, float scale_x, float half_h, float half_w)
{
    // XCD-aware swizzle: dispatch d lands on XCD d%8 -> contiguous work band.
    const int d   = blockIdx.x;
    const int per = nblocks / NXCD;
    const int work = (d % NXCD) * per + d / NXCD;
    const int y = work % H;
    const int b = work / H;
    const int tid = threadIdx.x;

    // padded, y-interpolated, PRE-SCALED control row:
    // slot pairs (c+1): [0] = x-shift*half_w, [1] = y-shift*half_h, c in [-1..17]
    __shared__ __align__(16) float s_row[40];

    if (tid < 38) {
        const int c  = (tid >> 1) - 1;
        const int cc = min(max(c, 0), CW - 1);
        const int ch = tid & 1;                      // source ch: 0=y, 1=x
        const float sy  = y * scale_y;
        const float fy0 = floorf(sy);
        const int   cy0 = (int)fy0;
        float wy[4];
        cubic_weights(sy - fy0, wy);
        float v = 0.0f;
        #pragma unroll
        for (int i = 0; i < 4; ++i) {
            const int cy = min(max(cy0 - 1 + i, 0), CH - 1);
            v += wy[i] * smap[(((size_t)b * CH + cy) * CW + cc) * 2 + ch];
        }
        const float scale = ch ? half_w : half_h;
        s_row[(c + 1) * 2 + (ch ^ 1)] = v * scale;   // swap: x first
    }
    __syncthreads();

    const f2* __restrict__ srow2 = reinterpret_cast<const f2*>(s_row);
    const float* imgb = img + (size_t)b * H * W;
    float* outb = out + (size_t)b * H * W + (size_t)y * W;

    #pragma unroll
    for (int k = 0; k < PX; ++k) {
        const int x = tid + k * 256;

        // ---- x-interp (packed): 4 ds_read_b64 + 4 pk-FMA ----
        const f4a wxv = wxtab[x];
        const int cx0 = (int)(x * scale_x);          // matches table's floor
        const f2 c0 = srow2[cx0],     c1 = srow2[cx0 + 1],
                 c2 = srow2[cx0 + 2], c3 = srow2[cx0 + 3];
        const f2 sm = wxv.x * c0 + wxv.y * c1 + wxv.z * c2 + wxv.w * c3;

        // ---- coords (packed) ----
        f2 xy; xy.x = (float)x; xy.y = (float)y;
        const f2 pos = xy + sm;                      // (ix, iy) in pixels
        const float ixf = floorf(pos.x), iyf = floorf(pos.y);
        const int ix0 = (int)ixf, iy0 = (int)iyf;
        f2 fl; fl.x = ixf; fl.y = iyf;
        const f2 t = pos - fl;
        f2 w0, w1, w2, w3;
        {
            f2 ww[4];
            cubic_weights_pk(t, ww);                 // .x = x-weight, .y = y-weight
            w0 = ww[0]; w1 = ww[1]; w2 = ww[2]; w3 = ww[3];
        }

        // ---- 4x4 bicubic gather ----
        float acc = 0.0f;
        if (__builtin_expect((ix0 >= 1) & (ix0 <= W - 3) &
                             (iy0 >= 1) & (iy0 <= H - 3), 1)) {
            const float* p = imgb + (size_t)(iy0 - 1) * W + (ix0 - 1);
            const f4u r0 = *reinterpret_cast<const f4u*>(p);
            const f4u r1 = *reinterpret_cast<const f4u*>(p + W);
            const f4u r2 = *reinterpret_cast<const f4u*>(p + 2 * W);
            const f4u r3 = *reinterpret_cast<const f4u*>(p + 3 * W);
            acc  = w0.y * (w0.x * r0.x + w1.x * r0.y + w2.x * r0.z + w3.x * r0.w);
            acc += w1.y * (w0.x * r1.x + w1.x * r1.y + w2.x * r1.z + w3.x * r1.w);
            acc += w2.y * (w0.x * r2.x + w1.x * r2.y + w2.x * r2.z + w3.x * r2.w);
            acc += w3.y * (w0.x * r3.x + w1.x * r3.y + w2.x * r3.z + w3.x * r3.w);
        } else {
            // border: zeros padding with per-tap masks (rare)
            const float gwx[4] = {w0.x, w1.x, w2.x, w3.x};
            const float gwy[4] = {w0.y, w1.y, w2.y, w3.y};
            #pragma unroll
            for (int i = 0; i < 4; ++i) {
                const int yy = iy0 - 1 + i;
                const bool vy = (yy >= 0) && (yy < H);
                const int yc = min(max(yy, 0), H - 1);
                const float* row = imgb + (size_t)yc * W;
                float r = 0.0f;
                #pragma unroll
                for (int j = 0; j < 4; ++j) {
                    const int xx = ix0 - 1 + j;
                    const bool v = vy && (xx >= 0) && (xx < W);
                    const int xc = min(max(xx, 0), W - 1);
                    r += gwx[j] * (v ? row[xc] : 0.0f);
                }
                acc += gwy[i] * r;
            }
        }
        outb[x] = acc;
    }
}

// ---- fallback (v8, no table) if ws_size is too small ----
template <int PX>
__global__ __launch_bounds__(256) void shiftmap_warp_fallback(
    const float* __restrict__ img, const float* __restrict__ smap,
    float* __restrict__ out, int H, int W, int CH, int CW, int nblocks)
{
    const int d   = blockIdx.x;
    const int per = nblocks / NXCD;
    const int work = (d % NXCD) * per + d / NXCD;
    const int y = work % H;
    const int b = work / H;
    const int tid = threadIdx.x;

    __shared__ float s_row[40];
    const float scale_y = (float)((double)(CH - 1) / (double)(H - 1));
    const float scale_x = (float)((double)(CW - 1) / (double)(W - 1));

    if (tid < 38) {
        const int c  = (tid >> 1) - 1;
        const int cc = min(max(c, 0), CW - 1);
        const int ch = tid & 1;
        const float sy  = y * scale_y;
        const float fy0 = floorf(sy);
        const int   cy0 = (int)fy0;
        float wy[4];
        cubic_weights(sy - fy0, wy);
        float v = 0.0f;
        #pragma unroll
        for (int i = 0; i < 4; ++i) {
            const int cy = min(max(cy0 - 1 + i, 0), CH - 1);
            v += wy[i] * smap[(((size_t)b * CH + cy) * CW + cc) * 2 + ch];
        }
        s_row[tid] = v;
    }
    __syncthreads();

    const float half_w = 0.5f * (float)(W - 1);
    const float half_h = 0.5f * (float)(H - 1);
    const float* imgb = img + (size_t)b * H * W;
    float* outb = out + (size_t)b * H * W + (size_t)y * W;

    #pragma unroll
    for (int k = 0; k < PX; ++k) {
        const int x = tid + k * 256;
        const float sx  = x * scale_x;
        const float fx0 = floorf(sx);
        const int   cx0 = (int)fx0;
        float wx[4];
        cubic_weights(sx - fx0, wx);
        const float* sr = s_row + cx0 * 2;
        const float smy = wx[0] * sr[0] + wx[1] * sr[2] + wx[2] * sr[4] + wx[3] * sr[6];
        const float smx = wx[0] * sr[1] + wx[1] * sr[3] + wx[2] * sr[5] + wx[3] * sr[7];
        const float ix = (float)x + smx * half_w;
        const float iy = (float)y + smy * half_h;
        const float ixf = floorf(ix), iyf = floorf(iy);
        const int ix0 = (int)ixf, iy0 = (int)iyf;
        float gwx[4], gwy[4];
        cubic_weights(ix - ixf, gwx);
        cubic_weights(iy - iyf, gwy);
        float acc = 0.0f;
        if ((ix0 >= 1) & (ix0 <= W - 3) & (iy0 >= 1) & (iy0 <= H - 3)) {
            const float* p = imgb + (size_t)(iy0 - 1) * W + (ix0 - 1);
            const f4u r0 = *reinterpret_cast<const f4u*>(p);
            const f4u r1 = *reinterpret_cast<const f4u*>(p + W);
            const f4u r2 = *reinterpret_cast<const f4u*>(p + 2 * W);
            const f4u r3 = *reinterpret_cast<const f4u*>(p + 3 * W);
            acc  = gwy[0] * (gwx[0] * r0.x + gwx[1] * r0.y + gwx[2] * r0.z + gwx[3] * r0.w);
            acc += gwy[1] * (gwx[0] * r1.x + gwx[1] * r1.y + gwx[2] * r1.z + gwx[3] * r1.w);
            acc += gwy[2] * (gwx[0] * r2.x + gwx[1] * r2.y + gwx[2] * r2.z + gwx[3] * r2.w);
            acc += gwy[3] * (gwx[0] * r3.x + gwx[1] * r3.y + gwx[2] * r3.z + gwx[3] * r3.w);
        } else {
            #pragma unroll
            for (int i = 0; i < 4; ++i) {
                const int yy = iy0 - 1 + i;
                const bool vy = (yy >= 0) && (yy < H);
                const int yc = min(max(yy, 0), H - 1);
                const float* row = imgb + (size_t)yc * W;
                float r = 0.0f;
                #pragma unroll
                for (int j = 0; j < 4; ++j) {
                    const int xx = ix0 - 1 + j;
                    const bool v = vy && (xx >= 0) && (xx < W);
                    const int xc = min(max(xx, 0), W - 1);
                    r += gwx[j] * (v ? row[xc] : 0.0f);
                }
                acc += gwy[i] * r;
            }
        }
        outb[x] = acc;
    }
}

extern "C" void kernel_launch(void* const* d_in, const int* in_sizes, int n_in,
                              void* d_out, int out_size, void* d_ws, size_t ws_size,
                              hipStream_t stream) {
    const float* img  = (const float*)d_in[0];  // (B,1,1024,1024) fp32
    const float* smap = (const float*)d_in[1];  // (B,16,16,2) fp32
    float* out = (float*)d_out;

    const int H = 1024, W = 1024;
    const int CH = 16, CW = 16;
    const int B = in_sizes[0] / (H * W);
    const int nblocks = H * B;

    const float scale_y = (float)((double)(CH - 1) / (double)(H - 1));
    const float scale_x = (float)((double)(CW - 1) / (double)(W - 1));
    const float half_h = 0.5f * (float)(H - 1);
    const float half_w = 0.5f * (float)(W - 1);

    const size_t ws_needed = (size_t)W * sizeof(f4a);
    if (ws_size >= ws_needed) {
        f4a* wxtab = (f4a*)d_ws;
        wxtab_kernel<<<dim3((W + 255) / 256), 256, 0, stream>>>(wxtab, W, scale_x);
        shiftmap_warp_kernel<4><<<dim3(nblocks), 256, 0, stream>>>(
            img, smap, wxtab, out, H, W, CH, CW, nblocks,
            scale_y, scale_x, half_h, half_w);
    } else {
        shiftmap_warp_fallback<4><<<dim3(nblocks), 256, 0, stream>>>(
            img, smap, out, H, W, CH, CW, nblocks);
    }
}

// Round 10
// 47.969 us; speedup vs baseline: 1.1764x; 1.1764x over previous
//
#include <hip/hip_runtime.h>

// ShiftMap fused, v10 = v8 skeleton + v9's arithmetic-only VALU cuts:
//  - single kernel, one block per (row,batch), 320B LDS control row, no table
//  - packed fp32 (v_pk_*) for: gather weights (gwx,gwy together), x-interp
//    (float2 control row, pre-scaled+swapped), coords
//  - wx weights recomputed per px in factored Keys form (cheap, no loads)
//  - interior fast path w/ 4 unaligned dwordx4 row-loads; border folds
//    zeros-padding into masks
//  - XCD-aware swizzle keeps each batch's 4MB image in one XCD's L2.

static constexpr float A = -0.75f;  // PyTorch bicubic coefficient
static constexpr int NXCD = 8;

typedef float f4u __attribute__((ext_vector_type(4), aligned(4)));
typedef float f2  __attribute__((ext_vector_type(2)));

__device__ __forceinline__ void cubic_weights(float t, float* w) {
    const float tm1 = t - 1.0f;
    const float p   = t * tm1;
    w[0] = (A * p) * tm1;            // A t (t-1)^2
    w[3] = (-A * p) * t;             // A t^2 (1-t)
    const float t2 = t * t;
    w[1] = (A + 2.0f) * t2 * t - (A + 3.0f) * t2 + 1.0f;
    w[2] = 1.0f - w[0] - w[1] - w[3];  // partition of unity
}

// packed pair: t = (tx, ty) -> w[j] = (wx_j, wy_j)
__device__ __forceinline__ void cubic_weights_pk(f2 t, f2* w) {
    const f2 tm1 = t - 1.0f;
    const f2 p   = t * tm1;
    w[0] = (A * p) * tm1;
    w[3] = (-A * p) * t;
    const f2 t2 = t * t;
    w[1] = (A + 2.0f) * t2 * t - (A + 3.0f) * t2 + 1.0f;
    w[2] = 1.0f - w[0] - w[1] - w[3];
}

template <int PX>
__global__ __launch_bounds__(256) void shiftmap_warp_kernel(
    const float* __restrict__ img,   // (B,1,H,W)
    const float* __restrict__ smap,  // (B,CH,CW,2)
    float* __restrict__ out,         // (B,1,H,W)
    int H, int W, int CH, int CW, int nblocks)
{
    // XCD-aware swizzle: dispatch d lands on XCD d%8 -> contiguous work band.
    const int d   = blockIdx.x;
    const int per = nblocks / NXCD;
    const int work = (d % NXCD) * per + d / NXCD;
    const int y = work % H;                    // image row
    const int b = work / H;                    // batch
    const int tid = threadIdx.x;

    // padded, y-interpolated, PRE-SCALED control row, x-channel first:
    // pair c+1 = (x_shift*half_w, y_shift*half_h), c in [-1..17]
    __shared__ __align__(8) float s_row[40];

    const float scale_y = (float)((double)(CH - 1) / (double)(H - 1));
    const float scale_x = (float)((double)(CW - 1) / (double)(W - 1));
    const float half_w = 0.5f * (float)(W - 1);
    const float half_h = 0.5f * (float)(H - 1);

    if (tid < 38) {
        const int c  = (tid >> 1) - 1;                 // -1..17
        const int cc = min(max(c, 0), CW - 1);         // clamp once at stage
        const int ch = tid & 1;                        // source ch: 0=y, 1=x
        const float sy  = y * scale_y;
        const float fy0 = floorf(sy);
        const int   cy0 = (int)fy0;
        float wy[4];
        cubic_weights(sy - fy0, wy);
        float v = 0.0f;
        #pragma unroll
        for (int i = 0; i < 4; ++i) {
            const int cy = min(max(cy0 - 1 + i, 0), CH - 1);
            v += wy[i] * smap[(((size_t)b * CH + cy) * CW + cc) * 2 + ch];
        }
        const float scale = ch ? half_w : half_h;
        s_row[(c + 1) * 2 + (ch ^ 1)] = v * scale;     // swapped: x first
    }
    __syncthreads();

    const f2* __restrict__ srow2 = reinterpret_cast<const f2*>(s_row);
    const float* imgb = img + (size_t)b * H * W;
    float* outb = out + (size_t)b * H * W + (size_t)y * W;

    #pragma unroll
    for (int k = 0; k < PX; ++k) {
        const int x = tid + k * 256;

        // ---- x-interp of control row (packed): 4 ds_read_b64 + 4 pk-FMA ----
        const float sx  = x * scale_x;
        const float fx0 = floorf(sx);
        const int   cx0 = (int)fx0;                    // 0..15
        float wx[4];
        cubic_weights(sx - fx0, wx);
        const f2 c0 = srow2[cx0],     c1 = srow2[cx0 + 1],
                 c2 = srow2[cx0 + 2], c3 = srow2[cx0 + 3];
        const f2 sm = wx[0] * c0 + wx[1] * c1 + wx[2] * c2 + wx[3] * c3;

        // ---- sampling coords (packed; mesh folded analytically) ----
        f2 xy; xy.x = (float)x; xy.y = (float)y;
        const f2 pos = xy + sm;                        // (ix, iy) in pixels
        const float ixf = floorf(pos.x), iyf = floorf(pos.y);
        const int ix0 = (int)ixf, iy0 = (int)iyf;
        f2 fl; fl.x = ixf; fl.y = iyf;
        f2 w0, w1, w2, w3;
        {
            f2 ww[4];
            cubic_weights_pk(pos - fl, ww);            // .x = x-wt, .y = y-wt
            w0 = ww[0]; w1 = ww[1]; w2 = ww[2]; w3 = ww[3];
        }

        // ---- 4x4 bicubic gather ----
        float acc = 0.0f;
        if (__builtin_expect((ix0 >= 1) & (ix0 <= W - 3) &
                             (iy0 >= 1) & (iy0 <= H - 3), 1)) {
            // interior fast path: 4 unaligned float4 row-loads
            const float* p = imgb + (size_t)(iy0 - 1) * W + (ix0 - 1);
            const f4u r0 = *reinterpret_cast<const f4u*>(p);
            const f4u r1 = *reinterpret_cast<const f4u*>(p + W);
            const f4u r2 = *reinterpret_cast<const f4u*>(p + 2 * W);
            const f4u r3 = *reinterpret_cast<const f4u*>(p + 3 * W);
            acc  = w0.y * (w0.x * r0.x + w1.x * r0.y + w2.x * r0.z + w3.x * r0.w);
            acc += w1.y * (w0.x * r1.x + w1.x * r1.y + w2.x * r1.z + w3.x * r1.w);
            acc += w2.y * (w0.x * r2.x + w1.x * r2.y + w2.x * r2.z + w3.x * r2.w);
            acc += w3.y * (w0.x * r3.x + w1.x * r3.y + w2.x * r3.z + w3.x * r3.w);
        } else {
            // border: zeros padding with per-tap masks (rare)
            const float gwx[4] = {w0.x, w1.x, w2.x, w3.x};
            const float gwy[4] = {w0.y, w1.y, w2.y, w3.y};
            #pragma unroll
            for (int i = 0; i < 4; ++i) {
                const int yy = iy0 - 1 + i;
                const bool vy = (yy >= 0) && (yy < H);
                const int yc = min(max(yy, 0), H - 1);
                const float* row = imgb + (size_t)yc * W;
                float r = 0.0f;
                #pragma unroll
                for (int j = 0; j < 4; ++j) {
                    const int xx = ix0 - 1 + j;
                    const bool v = vy && (xx >= 0) && (xx < W);
                    const int xc = min(max(xx, 0), W - 1);
                    r += gwx[j] * (v ? row[xc] : 0.0f);
                }
                acc += gwy[i] * r;
            }
        }
        outb[x] = acc;
    }
}

extern "C" void kernel_launch(void* const* d_in, const int* in_sizes, int n_in,
                              void* d_out, int out_size, void* d_ws, size_t ws_size,
                              hipStream_t stream) {
    const float* img  = (const float*)d_in[0];  // (B,1,1024,1024) fp32
    const float* smap = (const float*)d_in[1];  // (B,16,16,2) fp32
    float* out = (float*)d_out;

    const int H = 1024, W = 1024;
    const int CH = 16, CW = 16;
    const int B = in_sizes[0] / (H * W);
    const int nblocks = H * B;   // one block per (row, batch); 8192 (mult of 8)

    dim3 block(256);
    dim3 grid(nblocks);
    shiftmap_warp_kernel<4><<<grid, block, 0, stream>>>(img, smap, out,
                                                        H, W, CH, CW, nblocks);
}